// Round 5
// baseline (127.217 us; speedup 1.0000x reference)
//
#include <hip/hip_runtime.h>

#define GRID 32
#define NT 48
#define BLK 256
#define SPLIT 16                 // threads per point; each handles 3 t-rows = 9 tris
#define PPB (BLK / SPLIT)        // 16 points per block

// Per-edge packed info: bits [0]=base_x, [1]=base_y, [2]=base_z, [4:3]=axis.
#define EDGE_PACK ( (0ULL<<0) | (9ULL<<5) | (2ULL<<10) | (8ULL<<15) | \
                    (4ULL<<20) | (13ULL<<25) | (6ULL<<30) | (12ULL<<35) | \
                    (16ULL<<40) | (17ULL<<45) | (19ULL<<50) | (18ULL<<55) )

// Ericson closest-point-on-triangle on p-relative vectors Ap=p-a, Bp=p-b,
// Cp=p-c. All regions unified as q = a + ab*v + ac*w; the select cascade
// (reference `where` order, later wins) picks numerators (nv,nw) and a shared
// denominator, then ONE rcp serves every region (ref does 4 safe_divs, but
// only the selected region's quotient survives; conditions never depend on a
// quotient, so this is exact modulo ~1ulp rcp).
// Degenerate-bc fix: nv_bc = den_clamped - d43, so den==0 (b==c triangles,
// which random tri_table produces) yields v=1,w=0 -> q=b, matching ref.
__device__ float tri_dist_sq(float Apx, float Apy, float Apz,
                             float Bpx, float Bpy, float Bpz,
                             float Cpx, float Cpy, float Cpz) {
    float abx = Apx - Bpx, aby = Apy - Bpy, abz = Apz - Bpz;
    float acx = Apx - Cpx, acy = Apy - Cpy, acz = Apz - Cpz;
    float d1 = abx * Apx + aby * Apy + abz * Apz;
    float d2 = acx * Apx + acy * Apy + acz * Apz;
    float d3 = abx * Bpx + aby * Bpy + abz * Bpz;
    float d4 = acx * Bpx + acy * Bpy + acz * Bpz;
    float d5 = abx * Cpx + aby * Cpy + abz * Cpz;
    float d6 = acx * Cpx + acy * Cpy + acz * Cpz;
    float vc = d1 * d4 - d3 * d2;
    float vb = d5 * d2 - d1 * d6;
    float va = d3 * d6 - d5 * d4;
    float d43 = d4 - d3;
    float d56 = d5 - d6;

    bool c_bc = (va <= 0.0f) & (d43 >= 0.0f) & (d56 >= 0.0f);
    bool c_ac = (vb <= 0.0f) & (d2 >= 0.0f) & (d6 <= 0.0f);
    bool c_c  = (d6 >= 0.0f) & (d5 <= d6);
    bool c_ab = (vc <= 0.0f) & (d1 >= 0.0f) & (d3 <= 0.0f);
    bool c_b  = (d3 >= 0.0f) & (d4 <= d3);
    bool c_a  = (d1 <= 0.0f) & (d2 <= 0.0f);

    // denominator cascade (reference priority order), then clamp
    float den = va + vb + vc;
    den = c_bc ? (d43 + d56) : den;
    den = c_ac ? (d2 - d6)   : den;
    den = c_c  ? 1.0f        : den;
    den = c_ab ? (d1 - d3)   : den;
    den = (c_b | c_a) ? 1.0f : den;
    den = (fabsf(den) > 1e-12f) ? den : 1e-12f;
    float r = __builtin_amdgcn_rcpf(den);

    // w numerator cascade
    float nw = vc;
    nw = c_bc ? d43  : nw;
    nw = c_ac ? d2   : nw;
    nw = c_c  ? 1.0f : nw;
    nw = (c_ab | c_b | c_a) ? 0.0f : nw;

    // v numerator cascade (bc uses final clamped den: den - d43 == d56 in the
    // sane regime, and == eps -> v=1 in the degenerate clamp regime)
    float nv = vb;
    nv = c_bc ? (den - d43) : nv;
    nv = (c_ac | c_c) ? 0.0f : nv;
    nv = c_ab ? d1   : nv;
    nv = c_b  ? 1.0f : nv;
    nv = c_a  ? 0.0f : nv;

    float v = nv * r;
    float w = nw * r;
    float dx = Apx - abx * v - acx * w;
    float dy = Apy - aby * v - acy * w;
    float dz = Apz - abz * v - acz * w;
    return dx * dx + dy * dy + dz * dz;
}

__global__ __launch_bounds__(BLK) void ptd_kernel(
    const float* __restrict__ offset,     // (3,33,33,33)
    const float* __restrict__ points,     // (N,3)
    const int*   __restrict__ tri_table,  // (48,3,3)
    float*       __restrict__ out,        // (32768,48)
    int n)
{
    // Per-point rows of p-relative edge vertices: pv[e] = local - vert[e].
    // float4, row stride 13 -> row bank phases {0,5,2,7} mod 8, no systematic
    // whole-wave alignment.
    __shared__ float4 v_s[PPB * 13];
    // tri_table packed: one int per (t,k): i0 | i1<<8 | i2<<16.
    __shared__ int t_tab[NT * 3];

    const int tid = threadIdx.x;
    const int g   = blockIdx.x * BLK + tid;
    const int pt  = g >> 4;               // SPLIT=16
    const int grp = tid & 15;
    const int pl  = tid >> 4;             // point-local row (0..15)
    const bool active = (pt < n);

    if (tid < NT * 3) {
        int i0 = tri_table[tid * 3 + 0];
        int i1 = tri_table[tid * 3 + 1];
        int i2 = tri_table[tid * 3 + 2];
        t_tab[tid] = i0 | (i1 << 8) | (i2 << 16);
    }

    int cx = 0, cy = 0, cz = 0;
    if (active) {
        float px = points[pt * 3 + 0];
        float py = points[pt * 3 + 1];
        float pz = points[pt * 3 + 2];
        cx = min(max((int)floorf(px), 0), GRID - 1);
        cy = min(max((int)floorf(py), 0), GRID - 1);
        cz = min(max((int)floorf(pz), 0), GRID - 1);
        if (grp < 12) {
            float lx = px - (float)cx;
            float ly = py - (float)cy;
            float lz = pz - (float)cz;
            unsigned nib = (unsigned)(EDGE_PACK >> (5 * grp)) & 31u;
            int gx = cx + (int)(nib & 1u);
            int gy = cy + (int)((nib >> 1) & 1u);
            int gz = cz + (int)((nib >> 2) & 1u);
            int ax = (int)(nib >> 3);
            float t = offset[((ax * 33 + gx) * 33 + gy) * 33 + gz];
            float vx = (ax == 0) ? t : (float)(nib & 1u);
            float vy = (ax == 1) ? t : (float)((nib >> 1) & 1u);
            float vz = (ax == 2) ? t : (float)((nib >> 2) & 1u);
            v_s[pl * 13 + grp] = make_float4(lx - vx, ly - vy, lz - vz, 0.0f);
        }
    }
    __syncthreads();

    if (!active) return;

    const float4* vrow = &v_s[pl * 13];
    float* outp = out + ((((cx * GRID) + cy) * GRID + cz) * NT);

#pragma unroll
    for (int r = 0; r < 3; r++) {
        const int t = grp * 3 + r;
        float dmin;
#pragma unroll
        for (int k = 0; k < 3; k++) {
            int packed = t_tab[t * 3 + k];
            float4 A = vrow[packed & 255];
            float4 B = vrow[(packed >> 8) & 255];
            float4 C = vrow[(packed >> 16) & 255];
            float d = tri_dist_sq(A.x, A.y, A.z, B.x, B.y, B.z, C.x, C.y, C.z);
            dmin = (k == 0) ? d : fminf(dmin, d);
        }
        atomicAdd(&outp[t], dmin);
    }
}

extern "C" void kernel_launch(void* const* d_in, const int* in_sizes, int n_in,
                              void* d_out, int out_size, void* d_ws, size_t ws_size,
                              hipStream_t stream) {
    const float* offset    = (const float*)d_in[0];
    const float* points    = (const float*)d_in[1];
    const int*   tri_table = (const int*)d_in[2];
    float* out = (float*)d_out;
    int n = in_sizes[1] / 3;  // 131072 points

    // Output is accumulated via atomics; harness poisons d_out with 0xAA.
    hipMemsetAsync(d_out, 0, (size_t)out_size * sizeof(float), stream);

    long total = (long)n * SPLIT;
    int blocks = (int)((total + BLK - 1) / BLK);
    ptd_kernel<<<blocks, BLK, 0, stream>>>(offset, points, tri_table, out, n);
}